// Round 9
// baseline (79.177 us; speedup 1.0000x reference)
//
#include <hip/hip_runtime.h>
#include <hip/hip_bf16.h>
#include <stdint.h>

using f32x4  = __attribute__((ext_vector_type(4))) float;
using bf16x8 = __attribute__((ext_vector_type(8))) __bf16;
using bf16x4 = __attribute__((ext_vector_type(4))) __bf16;
using bf16x2 = __attribute__((ext_vector_type(2))) __bf16;
typedef unsigned int u32;

#define SEQ 4096

// D[q 4g+r][d c] += A[q c][k 4g+e] * B[k 4g+e][d c]   (K=16 keys)
__device__ __forceinline__ void mfma16(f32x4& acc, bf16x4 a, bf16x4 b) {
    asm volatile("v_mfma_f32_16x16x16_bf16 %0, %1, %2, %0"
                 : "+v"(acc) : "v"(a), "v"(b));
}

__global__ __launch_bounds__(1024, 4) void lattn_kern(
        const float* __restrict__ Q, const float* __restrict__ K,
        const float* __restrict__ V, float* __restrict__ O)
{
    // K: row-major [512 keys][64 dims] bf16, 16B-granule ^= (row&7)  (65536 B)
    __shared__ __bf16 Kl[512 * 64];
    // V^T: dim-major [64][520] bf16, row stride 1040 B (pad 65 granules) (66560 B)
    __shared__ __bf16 Vt[64 * 520];

    const int tid  = threadIdx.x;
    const int wv   = tid >> 6;     // 0..15
    const int lane = tid & 63;
    const int g    = lane >> 4;    // 0..3
    const int c    = lane & 15;    // 0..15
    const u32 swc  = (u32)(c & 7);

    // XCD-chunked swizzle: 1024 blocks = 8 XCDs x 128; same-head blocks colocate
    const int obid = blockIdx.x;
    const int bid  = (obid & 7) * 128 + (obid >> 3);
    const int b    = bid >> 4;     // head
    const int qb   = bid & 15;     // 256-query tile
    const int t0   = qb * 256;
    const size_t baseB = (size_t)b * (SEQ * 64);

    // ---------------- stage K: 512 rows x 8 dim-chunks ----------------
    #pragma unroll
    for (int it = 0; it < 4; ++it) {
        const int ch  = tid + it * 1024;
        const int row = ch >> 3, dg = ch & 7;
        const int grow = (t0 - 128 + row) & (SEQ - 1);
        const float* src = K + baseB + (size_t)grow * 64 + dg * 8;
        f32x4 k0 = *(const f32x4*)src, k1 = *(const f32x4*)(src + 4);
        bf16x8 hk;
        #pragma unroll
        for (int u = 0; u < 4; ++u) { hk[u] = (__bf16)k0[u]; hk[u + 4] = (__bf16)k1[u]; }
        *(bf16x8*)((char*)Kl + row * 128 + (((u32)dg ^ (u32)(row & 7)) << 4)) = hk;
    }

    // ---------------- stage V^T: 256 col-pairs x 8 dim-chunks ----------------
    #pragma unroll
    for (int it = 0; it < 2; ++it) {
        const int ch = tid + it * 1024;
        const int rp = ch >> 3, dg = ch & 7;
        const int grow = (t0 - 128 + 2 * rp) & (SEQ - 1);   // even: +1 never wraps
        const float* src = V + baseB + (size_t)grow * 64 + dg * 8;
        f32x4 a0 = *(const f32x4*)src,        a1 = *(const f32x4*)(src + 4);
        f32x4 b0 = *(const f32x4*)(src + 64), b1 = *(const f32x4*)(src + 68);
        #pragma unroll
        for (int u = 0; u < 8; ++u) {
            const int d = dg * 8 + u;
            bf16x2 pv;
            pv[0] = (__bf16)((u < 4) ? a0[u] : a1[u - 4]);
            pv[1] = (__bf16)((u < 4) ? b0[u] : b1[u - 4]);
            *(bf16x2*)((char*)Vt + (u32)d * 1040u + (u32)rp * 4u) = pv;
        }
    }

    // ---------------- Q fragments: rows t0 + 16wv + c ----------------
    bf16x8 aq0, aq1;
    {
        const float* qp = Q + baseB + (size_t)(t0 + wv * 16 + c) * 64 + g * 8;
        f32x4 q0 = *(const f32x4*)qp,        q1 = *(const f32x4*)(qp + 4);
        f32x4 q2 = *(const f32x4*)(qp + 32), q3 = *(const f32x4*)(qp + 36);
        #pragma unroll
        for (int u = 0; u < 4; ++u) {
            aq0[u] = (__bf16)q0[u]; aq0[u + 4] = (__bf16)q1[u];
            aq1[u] = (__bf16)q2[u]; aq1[u + 4] = (__bf16)q3[u];
        }
    }

    __syncthreads();   // the only barrier: staged window visible to all waves

    // ---------------- S^T = K Q^T : 17 tiles, lane holds [key 4g+r][query c] ----
    f32x4 s_[17];
    __builtin_amdgcn_s_setprio(1);
    #pragma unroll
    for (int lt = 0; lt < 17; ++lt) {
        const int row = 16 * wv + c + 16 * lt;        // < 512, row&7 == c&7
        const char* ka = (const char*)Kl + (u32)row * 128u;
        bf16x8 a0 = *(const bf16x8*)(ka + (((u32)g ^ swc) << 4));
        bf16x8 a1 = *(const bf16x8*)(ka + (((u32)(g + 4) ^ swc) << 4));
        f32x4 acc = {0.f, 0.f, 0.f, 0.f};
        acc = __builtin_amdgcn_mfma_f32_16x16x32_bf16(a0, aq0, acc, 0, 0, 0);
        acc = __builtin_amdgcn_mfma_f32_16x16x32_bf16(a1, aq1, acc, 0, 0, 0);
        s_[lt] = acc;
    }
    __builtin_amdgcn_s_setprio(0);

    // ---------------- softmax over keys of query 16wv+c (no max-subtract) ------
    const int k4 = 4 * g;
    float sum = 0.f;
    #pragma unroll
    for (int lt = 0; lt < 17; ++lt) {
        #pragma unroll
        for (int r = 0; r < 4; ++r) {
            float e = exp2f(s_[lt][r] * 0.18033688f);   // 0.125*log2(e)
            if (lt == 0)  e = (k4 + r <  c) ? 0.f : e;
            if (lt == 16) e = (k4 + r >= c) ? 0.f : e;
            s_[lt][r] = e; sum += e;
        }
    }
    sum += __shfl_xor(sum, 16, 64);
    sum += __shfl_xor(sum, 32, 64);
    const float inv = 1.0f / sum;

    // ---------------- P -> normalized bf16 A-frags, in-register ----------------
    bf16x4 pa[17];
    #pragma unroll
    for (int lt = 0; lt < 17; ++lt) {
        #pragma unroll
        for (int r = 0; r < 4; ++r) pa[lt][r] = (__bf16)(s_[lt][r] * inv);
    }

    // ---------------- O = P V ----------------
    f32x4 o[4] = {{0,0,0,0},{0,0,0,0},{0,0,0,0},{0,0,0,0}};
    const int cb = 16 * wv + 4 * g;
    __builtin_amdgcn_s_setprio(1);
    #pragma unroll
    for (int lt = 0; lt < 17; ++lt) {
        const int col = cb + 16 * lt;                 // < 512
        #pragma unroll
        for (int dt = 0; dt < 4; ++dt) {
            const int d = dt * 16 + c;
            const bf16x4 vbf = *(const bf16x4*)((const char*)Vt
                                + (u32)d * 1040u + (u32)col * 2u);
            mfma16(o[dt], pa[lt], vbf);
        }
    }
    __builtin_amdgcn_s_setprio(0);
    asm volatile("s_nop 7\n\ts_nop 7" ::);   // MFMA(asm)->VMEM read hazard guard

    // ---------------- store: lane (g,c) -> O[q 16wv+4g+r][d 16dt+c] ----------
    #pragma unroll
    for (int dt = 0; dt < 4; ++dt) {
        #pragma unroll
        for (int r = 0; r < 4; ++r) {
            const int row = t0 + wv * 16 + 4 * g + r;
            O[baseB + (size_t)row * 64 + dt * 16 + c] = o[dt][r];
        }
    }
}

extern "C" void kernel_launch(void* const* d_in, const int* in_sizes, int n_in,
                              void* d_out, int out_size, void* d_ws, size_t ws_size,
                              hipStream_t stream) {
    const float* q = (const float*)d_in[0];
    const float* k = (const float*)d_in[1];
    const float* v = (const float*)d_in[2];
    float* o = (float*)d_out;
    const int nB = in_sizes[0] / (SEQ * 64);   // 64
    dim3 grid(nB * 16), block(1024);
    hipLaunchKernelGGL(lattn_kern, grid, block, 0, stream, q, k, v, o);
}